// Round 1
// baseline (113.187 us; speedup 1.0000x reference)
//
#include <hip/hip_runtime.h>
#include <hip/hip_bf16.h>
#include <math.h>

#define NFREQ 1024      // N_FFT//2
#define NMELS 256
#define NNOTES 82
#define KMAXH 400

// ---------------- Kernel A: cols[n][fi] = sum_k omega*mask*gauss ----------------
// Gaussian std=5 -> support ~ +-80 Hz (16 sigma). Only harmonics with center
// within that window of f contribute; k range = [(f-80)/f0, (f+80)/f0].
__global__ void harm_cols(const float* __restrict__ omega,
                          const float* __restrict__ stdv,
                          const float* __restrict__ mask,
                          float* __restrict__ cols) {
    int gid = blockIdx.x * blockDim.x + threadIdx.x;
    if (gid >= NNOTES * NFREQ) return;
    int n  = gid >> 10;
    int fi = gid & 1023;
    float f  = 11025.0f * (float)fi / 1023.0f;           // jnp.linspace(0, 11025, 1024)
    float f0 = 27.5f * exp2f((float)n / 12.0f);
    const float RAD = 80.0f;                              // 16*sigma at sigma=5: exp(-128) ~ 0
    int klo = (int)ceilf((f - RAD) / f0);
    int khi = (int)floorf((f + RAD) / f0);
    if (klo < 1) klo = 1;
    if (khi > KMAXH) khi = KMAXH;
    float acc = 0.0f;
    for (int k = klo; k <= khi; ++k) {
        int idx = n * KMAXH + (k - 1);
        float mk = mask[idx];
        if (mk == 0.0f) continue;
        float c = f0 * (float)k;
        float s = stdv[idx];
        float d = (f - c) / s;
        float e = 0.5f * d * d;
        if (e > 90.0f) continue;                          // exp(-90) negligible
        acc += omega[idx] * mk * expf(-e);
    }
    cols[gid] = acc;
}

// ---------------- Kernel B: w[n][m] from mel projection + log compress ----------
__device__ inline double mel_to_hz_d(double m) {
    const double logstep = 0.06875177742094911;           // log(6.4)/27
    return (m >= 15.0) ? 1000.0 * exp(logstep * (m - 15.0)) : m * (200.0 / 3.0);
}

__global__ void harm_w(const float* __restrict__ cols, float* __restrict__ w) {
    int gid = blockIdx.x * blockDim.x + threadIdx.x;
    if (gid >= NNOTES * NMELS) return;
    int n = gid >> 8;
    int m = gid & 255;
    const double logstep = 0.06875177742094911;
    const double mel_max = 15.0 + log(11.025) / logstep;  // hz_to_mel(11025)
    double mf0 = mel_to_hz_d(mel_max * (double)m       / 257.0);
    double mf1 = mel_to_hz_d(mel_max * (double)(m + 1) / 257.0);
    double mf2 = mel_to_hz_d(mel_max * (double)(m + 2) / 257.0);
    double inv_lo = 1.0 / (mf1 - mf0);
    double inv_hi = 1.0 / (mf2 - mf1);
    double enorm  = 2.0 / (mf2 - mf0);
    // fftfreq for column fi is 11025*(fi+1)/1024 (weights[:,1:]). Support: ff in (mf0, mf2).
    int lo = (int)floor(mf0 * (1024.0 / 11025.0)) - 1;
    int hi = (int)ceil (mf2 * (1024.0 / 11025.0)) + 1;
    if (lo < 0) lo = 0;
    if (hi > 1023) hi = 1023;
    double acc = 0.0;
    for (int fi = lo; fi <= hi; ++fi) {
        double ff = 11025.0 * (double)(fi + 1) / 1024.0;
        double lower = (ff - mf0) * inv_lo;
        double upper = (mf2 - ff) * inv_hi;
        double wt = fmin(lower, upper);
        wt = fmax(0.0, wt) * enorm;
        acc += wt * (double)cols[n * NFREQ + fi];
    }
    float spec = (float)acc;
    const float X_MIN = -13.815510557964274f;             // log(1e-6)
    const float X_MAX = 3.0f;
    float x = logf(spec + 1e-6f);
    x = fminf(fmaxf(x, X_MIN), X_MAX);
    w[gid] = (x - X_MIN) * (1.0f / (X_MAX - X_MIN));
}

// ---------------- Kernel C: out[r][c] = sum_n y[r][n] * w[n][c] ------------------
// Block tile: 64 rows x 128 cols, 256 threads, each thread 8 rows x 4 cols.
#define BR 64
#define BC 128
__global__ __launch_bounds__(256) void harm_gemm(const float* __restrict__ y,
                                                 const float* __restrict__ w,
                                                 float* __restrict__ out) {
    __shared__ __align__(16) float y_lds[BR * NNOTES];    // 21 KB, row-major [r][n]
    __shared__ __align__(16) float w_lds[NNOTES * BC];    // 42 KB, row-major [n][c]
    int tid = threadIdx.x;
    int r0 = blockIdx.x * BR;
    int c0 = blockIdx.y * BC;

    // stage y tile: rows r0..r0+63, all 82 n -> contiguous 5248 floats
    {
        const float4* src = (const float4*)(y + (size_t)r0 * NNOTES);
        float4* dst = (float4*)y_lds;
        #pragma unroll
        for (int i = 0; i < (BR * NNOTES) / 4 / 256 + 1; ++i) {
            int j = tid + i * 256;
            if (j < (BR * NNOTES) / 4) dst[j] = src[j];
        }
    }
    // stage w tile: 82 rows x 32 float4
    {
        float4* dst = (float4*)w_lds;
        for (int j = tid; j < NNOTES * (BC / 4); j += 256) {
            int row = j >> 5;
            int c4  = j & 31;
            dst[j] = *(const float4*)(w + row * NMELS + c0 + c4 * 4);
        }
    }
    __syncthreads();

    int cg = tid & 31;        // 32 col-groups * 4 cols = 128 cols
    int rg = tid >> 5;        // 8 row-groups * 8 rows = 64 rows
    float4 acc[8];
    #pragma unroll
    for (int i = 0; i < 8; ++i) acc[i] = make_float4(0.f, 0.f, 0.f, 0.f);

    const float* yrow = y_lds + (rg * 8) * NNOTES;
    const float4* w4  = (const float4*)w_lds;
    #pragma unroll 2
    for (int n = 0; n < NNOTES; ++n) {
        float4 wv = w4[n * (BC / 4) + cg];
        #pragma unroll
        for (int i = 0; i < 8; ++i) {
            float yv = yrow[i * NNOTES + n];
            acc[i].x = fmaf(yv, wv.x, acc[i].x);
            acc[i].y = fmaf(yv, wv.y, acc[i].y);
            acc[i].z = fmaf(yv, wv.z, acc[i].z);
            acc[i].w = fmaf(yv, wv.w, acc[i].w);
        }
    }

    float* obase = out + (size_t)(r0 + rg * 8) * NMELS + c0 + cg * 4;
    #pragma unroll
    for (int i = 0; i < 8; ++i)
        *(float4*)(obase + (size_t)i * NMELS) = acc[i];
}

extern "C" void kernel_launch(void* const* d_in, const int* in_sizes, int n_in,
                              void* d_out, int out_size, void* d_ws, size_t ws_size,
                              hipStream_t stream) {
    const float* y     = (const float*)d_in[0];
    const float* omega = (const float*)d_in[1];
    const float* stdv  = (const float*)d_in[2];
    const float* mask  = (const float*)d_in[3];
    float* out  = (float*)d_out;
    float* cols = (float*)d_ws;                 // 82*1024 floats
    float* w    = cols + NNOTES * NFREQ;        // 82*256 floats

    int R = in_sizes[0] / NNOTES;               // 131072 rows

    harm_cols<<<(NNOTES * NFREQ + 255) / 256, 256, 0, stream>>>(omega, stdv, mask, cols);
    harm_w<<<(NNOTES * NMELS + 255) / 256, 256, 0, stream>>>(cols, w);

    dim3 grid(R / BR, NMELS / BC);
    harm_gemm<<<grid, 256, 0, stream>>>(y, w, out);
}

// Round 2
// 54.541 us; speedup vs baseline: 2.0753x; 2.0753x over previous
//
#include <hip/hip_runtime.h>
#include <hip/hip_bf16.h>
#include <math.h>

#define NFREQ 1024      // N_FFT//2
#define NMELS 256
#define NNOTES 82
#define KPAD  96        // K padded to multiple of 32 for mfma 16x16x32
#define KMAXH 400

typedef __attribute__((ext_vector_type(8))) short bf16x8;
typedef __attribute__((ext_vector_type(4))) float f32x4;

__device__ inline unsigned short f2bf(float x) {
    union { float f; unsigned int u; } c; c.f = x;
    unsigned int r = c.u + 0x7FFFu + ((c.u >> 16) & 1u);   // round-to-nearest-even
    return (unsigned short)(r >> 16);
}
__device__ inline float bf2f(unsigned short h) {
    union { unsigned int u; float f; } c; c.u = ((unsigned int)h) << 16; return c.f;
}

// ---------------- Kernel A: cols[n][fi] = sum_k omega*mask*gauss ----------------
__global__ void harm_cols(const float* __restrict__ omega,
                          const float* __restrict__ stdv,
                          const float* __restrict__ mask,
                          float* __restrict__ cols) {
    int gid = blockIdx.x * blockDim.x + threadIdx.x;
    if (gid >= NNOTES * NFREQ) return;
    int n  = gid >> 10;
    int fi = gid & 1023;
    float f  = 11025.0f * (float)fi / 1023.0f;
    float f0 = 27.5f * exp2f((float)n / 12.0f);
    const float RAD = 80.0f;
    int klo = (int)ceilf((f - RAD) / f0);
    int khi = (int)floorf((f + RAD) / f0);
    if (klo < 1) klo = 1;
    if (khi > KMAXH) khi = KMAXH;
    float acc = 0.0f;
    for (int k = klo; k <= khi; ++k) {
        int idx = n * KMAXH + (k - 1);
        float mk = mask[idx];
        if (mk == 0.0f) continue;
        float c = f0 * (float)k;
        float s = stdv[idx];
        float d = (f - c) / s;
        float e = 0.5f * d * d;
        if (e > 90.0f) continue;
        acc += omega[idx] * mk * expf(-e);
    }
    cols[gid] = acc;
}

// ---------------- Kernel B: wT_hi/lo[m][n] (transposed, K-padded, bf16 split) ---
__device__ inline double mel_to_hz_d(double m) {
    const double logstep = 0.06875177742094911;           // log(6.4)/27
    return (m >= 15.0) ? 1000.0 * exp(logstep * (m - 15.0)) : m * (200.0 / 3.0);
}

__global__ void harm_w(const float* __restrict__ cols,
                       unsigned short* __restrict__ wThi,
                       unsigned short* __restrict__ wTlo) {
    int gid = blockIdx.x * blockDim.x + threadIdx.x;
    if (gid >= NMELS * KPAD) return;
    int m = gid / KPAD;
    int n = gid - m * KPAD;
    if (n >= NNOTES) { wThi[gid] = 0; wTlo[gid] = 0; return; }
    const double logstep = 0.06875177742094911;
    const double mel_max = 15.0 + log(11.025) / logstep;  // hz_to_mel(11025)
    double mf0 = mel_to_hz_d(mel_max * (double)m       / 257.0);
    double mf1 = mel_to_hz_d(mel_max * (double)(m + 1) / 257.0);
    double mf2 = mel_to_hz_d(mel_max * (double)(m + 2) / 257.0);
    double inv_lo = 1.0 / (mf1 - mf0);
    double inv_hi = 1.0 / (mf2 - mf1);
    double enorm  = 2.0 / (mf2 - mf0);
    int lo = (int)floor(mf0 * (1024.0 / 11025.0)) - 1;
    int hi = (int)ceil (mf2 * (1024.0 / 11025.0)) + 1;
    if (lo < 0) lo = 0;
    if (hi > 1023) hi = 1023;
    double acc = 0.0;
    for (int fi = lo; fi <= hi; ++fi) {
        double ff = 11025.0 * (double)(fi + 1) / 1024.0;
        double lower = (ff - mf0) * inv_lo;
        double upper = (mf2 - ff) * inv_hi;
        double wt = fmin(lower, upper);
        wt = fmax(0.0, wt) * enorm;
        acc += wt * (double)cols[n * NFREQ + fi];
    }
    float spec = (float)acc;
    const float X_MIN = -13.815510557964274f;             // log(1e-6)
    const float X_MAX = 3.0f;
    float x = logf(spec + 1e-6f);
    x = fminf(fmaxf(x, X_MIN), X_MAX);
    float wv = (x - X_MIN) * (1.0f / (X_MAX - X_MIN));
    unsigned short h = f2bf(wv);
    wThi[gid] = h;
    wTlo[gid] = f2bf(wv - bf2f(h));
}

// ---------------- Kernel C: out = y @ w via split-bf16 MFMA ---------------------
// Block: 64 rows x 256 cols, 4 waves (each wave 64 rows x 64 cols).
// y staged once to LDS as pre-split bf16 hi/lo, K padded to 96 (stride 104).
__global__ __launch_bounds__(256) void harm_gemm(
    const float* __restrict__ y,
    const unsigned short* __restrict__ wThi,
    const unsigned short* __restrict__ wTlo,
    float* __restrict__ out)
{
    __shared__ unsigned short yhi[64][104];   // 13.3 KB
    __shared__ unsigned short ylo[64][104];   // 13.3 KB
    int tid = threadIdx.x;
    int m0 = blockIdx.x * 64;

    // ---- stage y tile, split f32 -> bf16 hi + lo ----
    int srow = tid >> 2, sch = tid & 3;       // 4 threads per row
    const float* yr = y + (size_t)(m0 + srow) * NNOTES;
    for (int s = sch; s < 41; s += 4) {       // 41 float2 per row (82 floats)
        float2 v = *(const float2*)(yr + 2 * s);
        unsigned short h0 = f2bf(v.x), h1 = f2bf(v.y);
        unsigned short l0 = f2bf(v.x - bf2f(h0)), l1 = f2bf(v.y - bf2f(h1));
        *(ushort2*)&yhi[srow][2 * s] = make_ushort2(h0, h1);
        *(ushort2*)&ylo[srow][2 * s] = make_ushort2(l0, l1);
    }
    for (int kk = NNOTES + sch; kk < KPAD; kk += 4) {     // zero K pad 82..95
        yhi[srow][kk] = 0; ylo[srow][kk] = 0;
    }
    __syncthreads();

    int lane = tid & 63;
    int wid  = tid >> 6;
    int r16  = lane & 15;
    int g4   = lane >> 4;
    int c0   = wid * 64;

    f32x4 acc[4][4];
    #pragma unroll
    for (int i = 0; i < 4; ++i)
        #pragma unroll
        for (int c = 0; c < 4; ++c) acc[i][c] = (f32x4){0.f, 0.f, 0.f, 0.f};

    #pragma unroll
    for (int kb = 0; kb < 3; ++kb) {
        int kof = kb * 32 + g4 * 8;
        bf16x8 bh[4], bl[4], ah[4], al[4];
        #pragma unroll
        for (int c = 0; c < 4; ++c) {
            size_t off = (size_t)(c0 + c * 16 + r16) * KPAD + kof;
            bh[c] = *(const bf16x8*)(wThi + off);
            bl[c] = *(const bf16x8*)(wTlo + off);
        }
        #pragma unroll
        for (int i = 0; i < 4; ++i) {
            ah[i] = *(const bf16x8*)&yhi[i * 16 + r16][kof];
            al[i] = *(const bf16x8*)&ylo[i * 16 + r16][kof];
        }
        #pragma unroll
        for (int i = 0; i < 4; ++i)
            #pragma unroll
            for (int c = 0; c < 4; ++c) {
                acc[i][c] = __builtin_amdgcn_mfma_f32_16x16x32_bf16(ah[i], bh[c], acc[i][c], 0, 0, 0);
                acc[i][c] = __builtin_amdgcn_mfma_f32_16x16x32_bf16(ah[i], bl[c], acc[i][c], 0, 0, 0);
                acc[i][c] = __builtin_amdgcn_mfma_f32_16x16x32_bf16(al[i], bh[c], acc[i][c], 0, 0, 0);
            }
    }

    // ---- write C: row = m0 + i*16 + g4*4 + q, col = c0 + c*16 + r16 ----
    #pragma unroll
    for (int i = 0; i < 4; ++i)
        #pragma unroll
        for (int q = 0; q < 4; ++q) {
            float* o = out + (size_t)(m0 + i * 16 + g4 * 4 + q) * NMELS + c0 + r16;
            #pragma unroll
            for (int c = 0; c < 4; ++c) o[c * 16] = acc[i][c][q];
        }
}

extern "C" void kernel_launch(void* const* d_in, const int* in_sizes, int n_in,
                              void* d_out, int out_size, void* d_ws, size_t ws_size,
                              hipStream_t stream) {
    const float* y     = (const float*)d_in[0];
    const float* omega = (const float*)d_in[1];
    const float* stdv  = (const float*)d_in[2];
    const float* mask  = (const float*)d_in[3];
    float* out = (float*)d_out;

    float* cols = (float*)d_ws;                                 // 82*1024 f32
    unsigned short* wThi = (unsigned short*)(cols + NNOTES * NFREQ);
    unsigned short* wTlo = wThi + NMELS * KPAD;

    int R = in_sizes[0] / NNOTES;                               // 131072 rows

    harm_cols<<<(NNOTES * NFREQ + 255) / 256, 256, 0, stream>>>(omega, stdv, mask, cols);
    harm_w<<<(NMELS * KPAD + 255) / 256, 256, 0, stream>>>(cols, wThi, wTlo);
    harm_gemm<<<R / 64, 256, 0, stream>>>(y, wThi, wTlo, out);
}